// Round 5
// baseline (2393.798 us; speedup 1.0000x reference)
//
#include <hip/hip_runtime.h>
#include <math.h>

#define NN 10000
#define EE 320000
#define GG 32
#define LL 6
#define TABN 4096
#define DTAB 5.45f
#define DCUT 5.4f

__device__ __forceinline__ float fsilu(float x) { return x / (1.0f + __expf(-x)); }
__device__ __forceinline__ float fgelu(float x) {
  float y = 0.7978845608f * (x + 0.044715f * x * x * x);
  float t = 1.0f - 2.0f / (__expf(2.0f * y) + 1.0f);
  return 0.5f * x * (1.0f + t);
}

// ---------------- CSR build ----------------
__global__ void k_hist(const int* __restrict__ dst, int* __restrict__ deg) {
  int e = blockIdx.x * blockDim.x + threadIdx.x;
  if (e < EE) atomicAdd(&deg[dst[e]], 1);
}

__global__ void k_scan(const int* __restrict__ cnt, int* __restrict__ off, int n) {
  __shared__ int sm[1024];
  __shared__ int carry_s;
  if (threadIdx.x == 0) { carry_s = 0; off[0] = 0; }
  __syncthreads();
  for (int base = 0; base < n; base += 1024) {
    int i = base + (int)threadIdx.x;
    int v = (i < n) ? cnt[i] : 0;
    sm[threadIdx.x] = v;
    __syncthreads();
    for (int o = 1; o < 1024; o <<= 1) {
      int t = (threadIdx.x >= o) ? sm[threadIdx.x - o] : 0;
      __syncthreads();
      sm[threadIdx.x] += t;
      __syncthreads();
    }
    if (i < n) off[i + 1] = carry_s + sm[threadIdx.x];
    __syncthreads();
    if (threadIdx.x == 0) carry_s += sm[1023];
    __syncthreads();
  }
}

__global__ void k_scatter(const int* __restrict__ dst, const int* __restrict__ row_off,
                          int* __restrict__ cursor, int* __restrict__ perm) {
  int e = blockIdx.x * blockDim.x + threadIdx.x;
  if (e < EE) {
    int d = dst[e];
    int p = atomicAdd(&cursor[d], 1);
    perm[row_off[d] + p] = e;
  }
}

// ---------------- distances in CSR order ----------------
__global__ void k_geom_d(const float* __restrict__ pos, const int* __restrict__ esrc,
                         const int* __restrict__ edst, const int* __restrict__ perm,
                         float* __restrict__ d_csr) {
  int j = blockIdx.x * blockDim.x + threadIdx.x;
  if (j >= EE) return;
  int e = perm[j];
  int s = esrc[e], dd = edst[e];
  float rx = pos[dd * 3 + 0] - pos[s * 3 + 0];
  float ry = pos[dd * 3 + 1] - pos[s * 3 + 1];
  float rz = pos[dd * 3 + 2] - pos[s * 3 + 2];
  d_csr[j] = sqrtf(rx * rx + ry * ry + rz * rz + 1e-6f);
}

// ---------------- active-edge list (d < DCUT) ----------------
__global__ void k_act_cnt(const int* __restrict__ row_off, const float* __restrict__ d_csr,
                          int* __restrict__ acnt) {
  int n = blockIdx.x * blockDim.x + threadIdx.x;
  if (n >= NN) return;
  int c = 0;
  for (int j = row_off[n]; j < row_off[n + 1]; ++j) c += (d_csr[j] < DCUT) ? 1 : 0;
  acnt[n] = c;
}

__global__ void k_act_fill(const int* __restrict__ row_off, const float* __restrict__ d_csr,
                           const int* __restrict__ act_off, int* __restrict__ act_idx) {
  int n = blockIdx.x * blockDim.x + threadIdx.x;
  if (n >= NN) return;
  int a = act_off[n];
  for (int j = row_off[n]; j < row_off[n + 1]; ++j)
    if (d_csr[j] < DCUT) act_idx[a++] = j;
}

// ---------------- compacted geometry per active edge ----------------
__global__ void k_geom_act(const int* __restrict__ act_idx, const int* __restrict__ perm,
                           const int* __restrict__ esrc, const int* __restrict__ edst,
                           const float* __restrict__ pos, const int* __restrict__ act_off,
                           float* __restrict__ d_a, int* __restrict__ src_a,
                           float* __restrict__ sh_a) {
  int a = blockIdx.x * blockDim.x + threadIdx.x;
  if (a >= act_off[NN]) return;
  int j = act_idx[a];
  int e = perm[j];
  int s = esrc[e], dd = edst[e];
  float rx = pos[dd * 3 + 0] - pos[s * 3 + 0];
  float ry = pos[dd * 3 + 1] - pos[s * 3 + 1];
  float rz = pos[dd * 3 + 2] - pos[s * 3 + 2];
  float d = sqrtf(rx * rx + ry * ry + rz * rz + 1e-6f);
  float inv = 1.0f / d;
  float x = rx * inv, y = ry * inv, z = rz * inv;
  d_a[a] = d;
  src_a[a] = s;
  const float s3 = 1.7320508075688772f;
  const float s5 = 2.23606797749979f;
  const float s15 = 3.872983346207417f;
  sh_a[a * 8 + 0] = s3 * x;
  sh_a[a * 8 + 1] = s3 * y;
  sh_a[a * 8 + 2] = s3 * z;
  sh_a[a * 8 + 3] = s15 * x * y;
  sh_a[a * 8 + 4] = s15 * y * z;
  sh_a[a * 8 + 5] = 0.5f * s5 * (3.0f * z * z - 1.0f);
  sh_a[a * 8 + 6] = s15 * x * z;
  sh_a[a * 8 + 7] = 0.5f * s15 * (x * x - y * y);
}

// ---------------- radial MLP table (all layers) ----------------
__global__ void k_build_wtab(const float* __restrict__ Wrad1, const float* __restrict__ brad1,
                             const float* __restrict__ Wrad2, const float* __restrict__ brad2,
                             float* __restrict__ wtab) {
  int l = blockIdx.x >> 6;
  int blk = blockIdx.x & 63;
  __shared__ float W1[128 * 64];
  __shared__ float W2[64 * 64];
  __shared__ float b1[64], b2[64];
  __shared__ float rbf_s[4][128];
  __shared__ float h_s[4][64];
  const float* w1p = Wrad1 + (size_t)l * 128 * 64;
  const float* w2p = Wrad2 + (size_t)l * 64 * 64;
  for (int i = threadIdx.x; i < 128 * 64; i += 256) W1[i] = w1p[i];
  for (int i = threadIdx.x; i < 64 * 64; i += 256) W2[i] = w2p[i];
  if (threadIdx.x < 64) {
    b1[threadIdx.x] = brad1[(size_t)l * 64 + threadIdx.x];
    b2[threadIdx.x] = brad2[(size_t)l * 64 + threadIdx.x];
  }
  __syncthreads();
  int wv = threadIdx.x >> 6, lane = threadIdx.x & 63;
  const float width = 5.0f / 128.0f;
  for (int k = wv; k < 64; k += 4) {
    int i = blk * 64 + k;
    float d = (float)i * (DTAB / (float)(TABN - 1));
    float c0 = (5.0f * (float)lane) / 127.0f;
    float c1 = (5.0f * (float)(lane + 64)) / 127.0f;
    float t0 = (d - c0) / width, t1 = (d - c1) / width;
    rbf_s[wv][lane] = __expf(-0.5f * t0 * t0);
    rbf_s[wv][lane + 64] = __expf(-0.5f * t1 * t1);
    float acc = b1[lane];
    #pragma unroll 8
    for (int i2 = 0; i2 < 128; i2++) acc += rbf_s[wv][i2] * W1[i2 * 64 + lane];
    acc = fsilu(acc);
    h_s[wv][lane] = acc;
    float acc2 = b2[lane];
    #pragma unroll 8
    for (int i2 = 0; i2 < 64; i2++) acc2 += h_s[wv][i2] * W2[i2 * 64 + lane];
    wtab[((size_t)l * TABN + i) * 64 + lane] = fsilu(acc2);
  }
}

// ---------------- init s ----------------
__global__ void k_init_s(const int* __restrict__ node_atom, const float* __restrict__ atom_emb,
                         float* __restrict__ s) {
  int i = blockIdx.x * blockDim.x + threadIdx.x;
  if (i < NN * 128) {
    int n = i >> 7, c = i & 127;
    s[i] = atom_emb[node_atom[n] * 128 + c];
  }
}

// ---------------- node transforms, 16 nodes/block ----------------
__global__ __launch_bounds__(256) void k_node_tf(
    const float* __restrict__ s, const float* __restrict__ v, const float* __restrict__ t,
    const float* __restrict__ Ws_src, const float* __restrict__ Ws_v,
    const float* __restrict__ Ws_t, const float* __restrict__ Wv_v,
    const float* __restrict__ Wt_t,
    float* __restrict__ sWsrc, float* __restrict__ sWv, float* __restrict__ sWt,
    float* __restrict__ vW, float* __restrict__ tW) {
  int nb = blockIdx.x * 16;
  int tid = threadIdx.x;
  __shared__ float s16[16][129];
  __shared__ float v16[16][192];
  __shared__ float t16[16][160];
  for (int idx = tid; idx < 16 * 128; idx += 256) {
    int n = idx >> 7, c = idx & 127;
    s16[n][c] = s[(size_t)(nb + n) * 128 + c];
  }
  for (int idx = tid; idx < 16 * 192; idx += 256) {
    int n = idx / 192, c = idx % 192;
    v16[n][c] = v[(size_t)(nb + n) * 192 + c];
  }
  for (int idx = tid; idx < 16 * 160; idx += 256) {
    int n = idx / 160, c = idx % 160;
    t16[n][c] = t[(size_t)(nb + n) * 160 + c];
  }
  __syncthreads();
  {
    int col = tid & 127, ng = tid >> 7;
    float acc[8] = {0, 0, 0, 0, 0, 0, 0, 0};
    for (int c = 0; c < 128; c++) {
      float w = Ws_src[c * 128 + col];
      #pragma unroll
      for (int n = 0; n < 8; n++) acc[n] += s16[ng * 8 + n][c] * w;
    }
    #pragma unroll
    for (int n = 0; n < 8; n++) sWsrc[(size_t)(nb + ng * 8 + n) * 128 + col] = acc[n];
  }
  {
    int col = tid & 63, ng = tid >> 6;
    float acc[4] = {0, 0, 0, 0};
    for (int c = 0; c < 128; c++) {
      float w = Ws_v[c * 64 + col];
      #pragma unroll
      for (int n = 0; n < 4; n++) acc[n] += s16[ng * 4 + n][c] * w;
    }
    #pragma unroll
    for (int n = 0; n < 4; n++) sWv[(size_t)(nb + ng * 4 + n) * 64 + col] = acc[n];
  }
  {
    int col = tid & 31, ng = tid >> 5;
    float acc[2] = {0, 0};
    for (int c = 0; c < 128; c++) {
      float w = Ws_t[c * 32 + col];
      acc[0] += s16[ng * 2 + 0][c] * w;
      acc[1] += s16[ng * 2 + 1][c] * w;
    }
    sWt[(size_t)(nb + ng * 2 + 0) * 32 + col] = acc[0];
    sWt[(size_t)(nb + ng * 2 + 1) * 32 + col] = acc[1];
  }
  {
    int dd = tid & 63, ng = tid >> 6;
    float acc[4][3] = {};
    for (int c = 0; c < 64; c++) {
      float w = Wv_v[c * 64 + dd];
      #pragma unroll
      for (int n = 0; n < 4; n++) {
        acc[n][0] += v16[ng * 4 + n][c * 3 + 0] * w;
        acc[n][1] += v16[ng * 4 + n][c * 3 + 1] * w;
        acc[n][2] += v16[ng * 4 + n][c * 3 + 2] * w;
      }
    }
    #pragma unroll
    for (int n = 0; n < 4; n++) {
      size_t b = (size_t)(nb + ng * 4 + n) * 192 + dd * 3;
      vW[b + 0] = acc[n][0];
      vW[b + 1] = acc[n][1];
      vW[b + 2] = acc[n][2];
    }
  }
  {
    int dd = tid & 31, ng = tid >> 5;
    float acc[2][5] = {};
    for (int c = 0; c < 32; c++) {
      float w = Wt_t[c * 32 + dd];
      #pragma unroll
      for (int n = 0; n < 2; n++)
        #pragma unroll
        for (int m = 0; m < 5; m++) acc[n][m] += t16[ng * 2 + n][c * 5 + m] * w;
    }
    #pragma unroll
    for (int n = 0; n < 2; n++) {
      size_t b = (size_t)(nb + ng * 2 + n) * 160 + dd * 5;
      #pragma unroll
      for (int m = 0; m < 5; m++) tW[b + m] = acc[n][m];
    }
  }
}

// ---------------- per-node attention query: q[n][i][h] ----------------
__global__ __launch_bounds__(256) void k_qvec(
    const float* __restrict__ sWsrc, const float* __restrict__ Ww_s,
    const float* __restrict__ attn_a, float* __restrict__ qv) {
  __shared__ float WqT[128][65];
  __shared__ float sW[16][130];
  int nb = blockIdx.x * 16;
  int tid = threadIdx.x;
  for (int idx = tid; idx < 64 * 128; idx += 256) {
    int i = idx >> 7, c = idx & 127;
    WqT[c][i] = Ww_s[i * 128 + c] * attn_a[c];
  }
  for (int idx = tid; idx < 16 * 128; idx += 256) {
    int n = idx >> 7, c = idx & 127;
    sW[n][c] = sWsrc[(size_t)(nb + n) * 128 + c];
  }
  __syncthreads();
  int i = tid & 63, ng = tid >> 6;
  for (int nn = 0; nn < 4; nn++) {
    int node = ng * 4 + nn;
    float q0 = 0.f, q1 = 0.f, q2 = 0.f, q3 = 0.f;
    for (int c = 0; c < 32; c++) {
      q0 += sW[node][c] * WqT[c][i];
      q1 += sW[node][32 + c] * WqT[32 + c][i];
      q2 += sW[node][64 + c] * WqT[64 + c][i];
      q3 += sW[node][96 + c] * WqT[96 + c][i];
    }
    *(float4*)&qv[(size_t)(nb + node) * 256 + i * 4] = make_float4(q0, q1, q2, q3);
  }
}

// ---------------- logits per active edge (via qvec) ----------------
__global__ __launch_bounds__(256) void k_logit(
    const float* __restrict__ d_a, const int* __restrict__ src_a,
    const int* __restrict__ act_off, const float* __restrict__ wtabL,
    const float* __restrict__ qv, float* __restrict__ logitb) {
  int EA = act_off[NN];
  int wv = threadIdx.x >> 6, lane = threadIdx.x & 63;
  int nG = (EA + 3) >> 2;
  for (int g = blockIdx.x * 4 + wv; g < nG; g += gridDim.x * 4) {
    int a0 = g * 4;
    int nv = EA - a0; if (nv > 4) nv = 4;
    #pragma unroll
    for (int k = 0; k < 4; k++) {
      if (k >= nv) break;
      int a = a0 + k;
      float x = d_a[a] * ((float)(TABN - 1) / DTAB);
      x = fminf(x, (float)(TABN - 1) - 1.0f);
      int i0 = (int)x; float f = x - (float)i0;
      const float* tp = wtabL + (size_t)i0 * 64 + lane;
      float wk = tp[0] * (1.0f - f) + tp[64] * f;
      int sn = src_a[a];
      float4 q4 = *(const float4*)&qv[(size_t)sn * 256 + lane * 4];
      float p0 = wk * q4.x, p1 = wk * q4.y, p2 = wk * q4.z, p3 = wk * q4.w;
      for (int mm = 1; mm < 64; mm <<= 1) {
        p0 += __shfl_xor(p0, mm);
        p1 += __shfl_xor(p1, mm);
        p2 += __shfl_xor(p2, mm);
        p3 += __shfl_xor(p3, mm);
      }
      if (lane == 0) *(float4*)&logitb[(size_t)a * 4] = make_float4(p0, p1, p2, p3);
    }
  }
}

// ---------------- fused scalar message + aggregation (wave per node) ----------------
__global__ __launch_bounds__(512, 4) void k_fused_s(
    const int* __restrict__ row_off, const int* __restrict__ act_off,
    const int* __restrict__ src_a, const float* __restrict__ d_a,
    const float* __restrict__ logitb, const float* __restrict__ wtabL,
    const float* __restrict__ sWsrc, const float* __restrict__ Ww_s,
    float* __restrict__ agg_s) {
  __shared__ float Wp[64 * 128];
  __shared__ float w4[8][64][4];
  int tid = threadIdx.x;
  for (int i = tid; i < 64 * 128; i += 512) {
    int r = i >> 7, cc = i & 127;
    int col = (cc >> 1) + ((cc & 1) ? 64 : 0);
    Wp[i] = Ww_s[r * 128 + col];
  }
  __syncthreads();
  int wv = tid >> 6, lane = tid & 63;
  int n = blockIdx.x * 8 + wv;
  int alo = act_off[n], ahi = act_off[n + 1];
  int nact = ahi - alo;
  int ninact = (row_off[n + 1] - row_off[n]) - nact;
  int h = lane & 3, slot = lane >> 2;
  float mxh = (ninact > 0) ? 0.0f : -1e30f;
  for (int idx = slot; idx < nact; idx += 16)
    mxh = fmaxf(mxh, logitb[(size_t)(alo + idx) * 4 + h]);
  for (int mm = 4; mm < 64; mm <<= 1) mxh = fmaxf(mxh, __shfl_xor(mxh, mm));
  float dh = 0.f;
  for (int idx = slot; idx < nact; idx += 16)
    dh += __expf(logitb[(size_t)(alo + idx) * 4 + h] - mxh);
  for (int mm = 4; mm < 64; mm <<= 1) dh += __shfl_xor(dh, mm);
  if (ninact > 0) dh += (float)ninact * __expf(0.0f - mxh);
  float rh = 1.0f / (dh + 1e-9f);
  float mx0 = __shfl(mxh, 0), mx1 = __shfl(mxh, 1), mx2 = __shfl(mxh, 2), mx3 = __shfl(mxh, 3);
  float r0 = __shfl(rh, 0), r1 = __shfl(rh, 1), r2 = __shfl(rh, 2), r3 = __shfl(rh, 3);
  float as0 = 0.f, as1 = 0.f;
  for (int a0 = alo; a0 < ahi; a0 += 4) {
    int nv = ahi - a0; if (nv > 4) nv = 4;
    float wk[4];
    #pragma unroll
    for (int k = 0; k < 4; k++) {
      int aa = (k < nv) ? (a0 + k) : a0;
      float x = d_a[aa] * ((float)(TABN - 1) / DTAB);
      x = fminf(x, (float)(TABN - 1) - 1.0f);
      int i0 = (int)x; float f = x - (float)i0;
      const float* tp = wtabL + (size_t)i0 * 64 + lane;
      wk[k] = tp[0] * (1.0f - f) + tp[64] * f;
    }
    *(float4*)&w4[wv][lane][0] = make_float4(wk[0], wk[1], wk[2], wk[3]);
    float m0k[4] = {0, 0, 0, 0}, m1k[4] = {0, 0, 0, 0};
    #pragma unroll 8
    for (int i = 0; i < 64; i++) {
      float4 wb = *(const float4*)&w4[wv][i][0];
      float2 wp = *(const float2*)&Wp[i * 128 + 2 * lane];
      m0k[0] += wb.x * wp.x; m1k[0] += wb.x * wp.y;
      m0k[1] += wb.y * wp.x; m1k[1] += wb.y * wp.y;
      m0k[2] += wb.z * wp.x; m1k[2] += wb.z * wp.y;
      m0k[3] += wb.w * wp.x; m1k[3] += wb.w * wp.y;
    }
    #pragma unroll
    for (int k = 0; k < 4; k++) {
      if (k >= nv) break;
      int a = a0 + k;
      float4 lg = *(const float4*)&logitb[(size_t)a * 4];
      float al0 = __expf(lg.x - mx0) * r0;
      float al1 = __expf(lg.y - mx1) * r1;
      float al2 = __expf(lg.z - mx2) * r2;
      float al3 = __expf(lg.w - mx3) * r3;
      float alS0 = (lane < 32) ? al0 : al1;
      float alS1 = (lane < 32) ? al2 : al3;
      int sn = src_a[a];
      as0 += alS0 * (sWsrc[(size_t)sn * 128 + lane] * m0k[k]);
      as1 += alS1 * (sWsrc[(size_t)sn * 128 + 64 + lane] * m1k[k]);
    }
  }
  agg_s[(size_t)n * 128 + lane] = as0;
  agg_s[(size_t)n * 128 + 64 + lane] = as1;
}

// ---------------- fused vector/tensor message + aggregation ----------------
__global__ __launch_bounds__(512, 4) void k_fused_vt(
    const int* __restrict__ row_off, const int* __restrict__ act_off,
    const int* __restrict__ src_a, const float* __restrict__ d_a,
    const float* __restrict__ logitb, const float* __restrict__ wtabL,
    const float* __restrict__ sWv, const float* __restrict__ sWt,
    const float* __restrict__ vW, const float* __restrict__ tW,
    const float* __restrict__ sh_a,
    const float* __restrict__ Ww_v, const float* __restrict__ Ww_vv,
    const float* __restrict__ Ww_t, const float* __restrict__ Ww_tt,
    float* __restrict__ agg_v, float* __restrict__ agg_t) {
  __shared__ float WVp[64 * 128];
  __shared__ float WTp[64 * 64];
  __shared__ float w4[8][64][4];
  int tid = threadIdx.x;
  for (int i = tid; i < 64 * 128; i += 512) {
    int r = i >> 7, cc = i & 127;
    int col = cc >> 1;
    WVp[i] = (cc & 1) ? Ww_vv[r * 64 + col] : Ww_v[r * 64 + col];
  }
  for (int i = tid; i < 64 * 64; i += 512) {
    int r = i >> 6, cc = i & 63;
    int c = cc >> 1;
    WTp[i] = (cc & 1) ? Ww_tt[r * 32 + c] : Ww_t[r * 32 + c];
  }
  __syncthreads();
  int wv = tid >> 6, lane = tid & 63;
  int n = blockIdx.x * 8 + wv;
  int alo = act_off[n], ahi = act_off[n + 1];
  int nact = ahi - alo;
  int ninact = (row_off[n + 1] - row_off[n]) - nact;
  int h = lane & 3, slot = lane >> 2;
  float mxh = (ninact > 0) ? 0.0f : -1e30f;
  for (int idx = slot; idx < nact; idx += 16)
    mxh = fmaxf(mxh, logitb[(size_t)(alo + idx) * 4 + h]);
  for (int mm = 4; mm < 64; mm <<= 1) mxh = fmaxf(mxh, __shfl_xor(mxh, mm));
  float dh = 0.f;
  for (int idx = slot; idx < nact; idx += 16)
    dh += __expf(logitb[(size_t)(alo + idx) * 4 + h] - mxh);
  for (int mm = 4; mm < 64; mm <<= 1) dh += __shfl_xor(dh, mm);
  if (ninact > 0) dh += (float)ninact * __expf(0.0f - mxh);
  float rh = 1.0f / (dh + 1e-9f);
  float mx0 = __shfl(mxh, 0), mx1 = __shfl(mxh, 1), mx2 = __shfl(mxh, 2), mx3 = __shfl(mxh, 3);
  float r0 = __shfl(rh, 0), r1 = __shfl(rh, 1), r2 = __shfl(rh, 2), r3 = __shfl(rh, 3);
  float av0 = 0.f, av1 = 0.f, av2 = 0.f;
  float at0 = 0.f, at1 = 0.f, at2 = 0.f, at3 = 0.f, at4 = 0.f;
  int lt = lane & 31;
  for (int a0 = alo; a0 < ahi; a0 += 4) {
    int nv = ahi - a0; if (nv > 4) nv = 4;
    float wk[4];
    #pragma unroll
    for (int k = 0; k < 4; k++) {
      int aa = (k < nv) ? (a0 + k) : a0;
      float x = d_a[aa] * ((float)(TABN - 1) / DTAB);
      x = fminf(x, (float)(TABN - 1) - 1.0f);
      int i0 = (int)x; float f = x - (float)i0;
      const float* tp = wtabL + (size_t)i0 * 64 + lane;
      wk[k] = tp[0] * (1.0f - f) + tp[64] * f;
    }
    *(float4*)&w4[wv][lane][0] = make_float4(wk[0], wk[1], wk[2], wk[3]);
    float avk[4] = {0, 0, 0, 0}, bvk[4] = {0, 0, 0, 0};
    float atk[4] = {0, 0, 0, 0}, btk[4] = {0, 0, 0, 0};
    #pragma unroll 4
    for (int i = 0; i < 64; i++) {
      float4 wb = *(const float4*)&w4[wv][i][0];
      float2 wp = *(const float2*)&WVp[i * 128 + 2 * lane];
      float2 wt = *(const float2*)&WTp[i * 64 + 2 * lt];
      avk[0] += wb.x * wp.x; bvk[0] += wb.x * wp.y; atk[0] += wb.x * wt.x; btk[0] += wb.x * wt.y;
      avk[1] += wb.y * wp.x; bvk[1] += wb.y * wp.y; atk[1] += wb.y * wt.x; btk[1] += wb.y * wt.y;
      avk[2] += wb.z * wp.x; bvk[2] += wb.z * wp.y; atk[2] += wb.z * wt.x; btk[2] += wb.z * wt.y;
      avk[3] += wb.w * wp.x; bvk[3] += wb.w * wp.y; atk[3] += wb.w * wt.x; btk[3] += wb.w * wt.y;
    }
    #pragma unroll
    for (int k = 0; k < 4; k++) {
      if (k >= nv) break;
      int a = a0 + k;
      float4 lg = *(const float4*)&logitb[(size_t)a * 4];
      float al0 = __expf(lg.x - mx0) * r0;
      float al1 = __expf(lg.y - mx1) * r1;
      float al2 = __expf(lg.z - mx2) * r2;
      float al3 = __expf(lg.w - mx3) * r3;
      float alV = (lane < 16) ? al0 : (lane < 32) ? al1 : (lane < 48) ? al2 : al3;
      int sn = src_a[a];
      float avv = sWv[(size_t)sn * 64 + lane] * avk[k];
      float bvv = bvk[k];
      float4 s1 = *(const float4*)&sh_a[(size_t)a * 8];
      float4 s2 = *(const float4*)&sh_a[(size_t)a * 8 + 4];
      const float* vp = &vW[(size_t)sn * 192 + lane * 3];
      av0 += alV * (avv * s1.x + vp[0] * bvv);
      av1 += alV * (avv * s1.y + vp[1] * bvv);
      av2 += alV * (avv * s1.z + vp[2] * bvv);
      if (lane < 32) {
        float alT = (lane < 16) ? ((lane < 8) ? al0 : al1) : ((lane < 24) ? al2 : al3);
        float att = sWt[(size_t)sn * 32 + lane] * atk[k];
        float btt = btk[k];
        const float* tp = &tW[(size_t)sn * 160 + lane * 5];
        at0 += alT * (att * s1.w + tp[0] * btt);
        at1 += alT * (att * s2.x + tp[1] * btt);
        at2 += alT * (att * s2.y + tp[2] * btt);
        at3 += alT * (att * s2.z + tp[3] * btt);
        at4 += alT * (att * s2.w + tp[4] * btt);
      }
    }
  }
  agg_v[(size_t)n * 192 + lane * 3 + 0] = av0;
  agg_v[(size_t)n * 192 + lane * 3 + 1] = av1;
  agg_v[(size_t)n * 192 + lane * 3 + 2] = av2;
  if (lane < 32) {
    agg_t[(size_t)n * 160 + lane * 5 + 0] = at0;
    agg_t[(size_t)n * 160 + lane * 5 + 1] = at1;
    agg_t[(size_t)n * 160 + lane * 5 + 2] = at2;
    agg_t[(size_t)n * 160 + lane * 5 + 3] = at3;
    agg_t[(size_t)n * 160 + lane * 5 + 4] = at4;
  }
}

// ---------------- node update, 16 nodes/block, ping-pong LDS ----------------
__global__ __launch_bounds__(256) void k_node_up(
    float* __restrict__ s, float* __restrict__ v, float* __restrict__ t,
    const float* __restrict__ agg_s, const float* __restrict__ agg_v,
    const float* __restrict__ agg_t, const float* __restrict__ Wo_s,
    const float* __restrict__ Wo_v, const float* __restrict__ Wo_t,
    const float* __restrict__ g_s, const float* __restrict__ b_s,
    const float* __restrict__ g_v, const float* __restrict__ g_t) {
  int nb = blockIdx.x * 16;
  int tid = threadIdx.x;
  __shared__ float bin[16][193];
  __shared__ float bout[16][193];
  // ---- S phase ----
  for (int idx = tid; idx < 16 * 128; idx += 256) {
    int n = idx >> 7, c = idx & 127;
    bin[n][c] = agg_s[(size_t)(nb + n) * 128 + c];
  }
  __syncthreads();
  {
    int col = tid & 127, ng = tid >> 7;
    float acc[8];
    #pragma unroll
    for (int n = 0; n < 8; n++) acc[n] = s[(size_t)(nb + ng * 8 + n) * 128 + col];
    for (int c = 0; c < 128; c++) {
      float w = Wo_s[c * 128 + col];
      #pragma unroll
      for (int n = 0; n < 8; n++) acc[n] += bin[ng * 8 + n][c] * w;
    }
    #pragma unroll
    for (int n = 0; n < 8; n++) bout[ng * 8 + n][col] = acc[n];
  }
  __syncthreads();
  // preload agg_v into bin (bin reads done at last sync); LayerNorm from bout
  for (int idx = tid; idx < 16 * 192; idx += 256) {
    int n = idx / 192, c = idx % 192;
    bin[n][c] = agg_v[(size_t)(nb + n) * 192 + c];
  }
  {
    int node = tid >> 4, q = tid & 15;
    float sm = 0.f, sq = 0.f;
    #pragma unroll
    for (int u = 0; u < 8; u++) {
      float x = bout[node][q * 8 + u];
      sm += x; sq += x * x;
    }
    sm += __shfl_xor(sm, 1); sq += __shfl_xor(sq, 1);
    sm += __shfl_xor(sm, 2); sq += __shfl_xor(sq, 2);
    sm += __shfl_xor(sm, 4); sq += __shfl_xor(sq, 4);
    sm += __shfl_xor(sm, 8); sq += __shfl_xor(sq, 8);
    float mu = sm / 128.0f;
    float var = sq / 128.0f - mu * mu;
    if (var < 0.f) var = 0.f;
    float ri = rsqrtf(var + 1e-6f);
    #pragma unroll
    for (int u = 0; u < 8; u++) {
      int c = q * 8 + u;
      s[(size_t)(nb + node) * 128 + c] = (bout[node][c] - mu) * ri * g_s[c] + b_s[c];
    }
  }
  __syncthreads();
  // ---- V phase ----
  {
    int dd = tid & 63, ng = tid >> 6;
    float acc[4][3];
    #pragma unroll
    for (int n = 0; n < 4; n++)
      #pragma unroll
      for (int i = 0; i < 3; i++)
        acc[n][i] = v[(size_t)(nb + ng * 4 + n) * 192 + dd * 3 + i];
    for (int c = 0; c < 64; c++) {
      float w = Wo_v[c * 64 + dd];
      #pragma unroll
      for (int n = 0; n < 4; n++) {
        acc[n][0] += bin[ng * 4 + n][c * 3 + 0] * w;
        acc[n][1] += bin[ng * 4 + n][c * 3 + 1] * w;
        acc[n][2] += bin[ng * 4 + n][c * 3 + 2] * w;
      }
    }
    __syncthreads();  // LN done reading bout
    #pragma unroll
    for (int n = 0; n < 4; n++)
      #pragma unroll
      for (int i = 0; i < 3; i++) bout[ng * 4 + n][dd * 3 + i] = acc[n][i];
  }
  __syncthreads();
  for (int idx = tid; idx < 16 * 160; idx += 256) {
    int n = idx / 160, c = idx % 160;
    bin[n][c] = agg_t[(size_t)(nb + n) * 160 + c];
  }
  {
    int node = tid >> 4, q = tid & 15;
    float ssq = 0.f;
    #pragma unroll
    for (int u = 0; u < 12; u++) {
      float x = bout[node][q * 12 + u];
      ssq += x * x;
    }
    ssq += __shfl_xor(ssq, 1);
    ssq += __shfl_xor(ssq, 2);
    ssq += __shfl_xor(ssq, 4);
    ssq += __shfl_xor(ssq, 8);
    float ri = rsqrtf(ssq / 64.0f + 1e-6f);
    #pragma unroll
    for (int u = 0; u < 12; u++) {
      int o = q * 12 + u;
      v[(size_t)(nb + node) * 192 + o] = bout[node][o] * ri * g_v[o / 3];
    }
  }
  __syncthreads();
  // ---- T phase ----
  {
    int dd = tid & 31, ng = tid >> 5;
    float acc[2][5];
    #pragma unroll
    for (int n = 0; n < 2; n++)
      #pragma unroll
      for (int m = 0; m < 5; m++)
        acc[n][m] = t[(size_t)(nb + ng * 2 + n) * 160 + dd * 5 + m];
    for (int c = 0; c < 32; c++) {
      float w = Wo_t[c * 32 + dd];
      #pragma unroll
      for (int n = 0; n < 2; n++)
        #pragma unroll
        for (int m = 0; m < 5; m++) acc[n][m] += bin[ng * 2 + n][c * 5 + m] * w;
    }
    __syncthreads();  // v-RMS done reading bout
    #pragma unroll
    for (int n = 0; n < 2; n++)
      #pragma unroll
      for (int m = 0; m < 5; m++) bout[ng * 2 + n][dd * 5 + m] = acc[n][m];
  }
  __syncthreads();
  {
    int node = tid >> 4, q = tid & 15;
    float ssq = 0.f;
    #pragma unroll
    for (int u = 0; u < 10; u++) {
      float x = bout[node][q * 10 + u];
      ssq += x * x;
    }
    ssq += __shfl_xor(ssq, 1);
    ssq += __shfl_xor(ssq, 2);
    ssq += __shfl_xor(ssq, 4);
    ssq += __shfl_xor(ssq, 8);
    float ri = rsqrtf(ssq / 32.0f + 1e-6f);
    #pragma unroll
    for (int u = 0; u < 10; u++) {
      int o = q * 10 + u;
      t[(size_t)(nb + node) * 160 + o] = bout[node][o] * ri * g_t[o / 5];
    }
  }
}

// ---------------- readout ----------------
__global__ __launch_bounds__(256) void k_readout(
    const float* __restrict__ s, const int* __restrict__ batch,
    const float* __restrict__ W_feat, const float* __restrict__ b_feat,
    const float* __restrict__ W_out1, const float* __restrict__ b_out1,
    float* __restrict__ graph) {
  __shared__ float st[64 * 129];
  __shared__ float red[16][67];
  __shared__ float gacc[GG];
  int nb = blockIdx.x * 64;
  int fb = blockIdx.y;
  for (int idx = threadIdx.x; idx < 64 * 128; idx += 256) {
    int nl = idx >> 7, c = idx & 127;
    int n = nb + nl;
    st[nl * 129 + c] = (n < NN) ? s[(size_t)n * 128 + c] : 0.f;
  }
  if (threadIdx.x < GG) gacc[threadIdx.x] = 0.f;
  __syncthreads();
  int ny = threadIdx.x & 15, fy = threadIdx.x >> 4;
  int f0 = fb * 64 + fy * 4;
  float acc[4][4];
  #pragma unroll
  for (int q = 0; q < 4; q++)
    #pragma unroll
    for (int kf = 0; kf < 4; kf++) acc[q][kf] = b_feat[f0 + kf];
  #pragma unroll 4
  for (int c = 0; c < 128; c++) {
    float4 wq = *(const float4*)&W_feat[(size_t)c * 512 + f0];
    #pragma unroll
    for (int q = 0; q < 4; q++) {
      float sv = st[(4 * ny + q) * 129 + c];
      acc[q][0] += sv * wq.x;
      acc[q][1] += sv * wq.y;
      acc[q][2] += sv * wq.z;
      acc[q][3] += sv * wq.w;
    }
  }
  float wo[4];
  #pragma unroll
  for (int kf = 0; kf < 4; kf++) wo[kf] = W_out1[f0 + kf];
  #pragma unroll
  for (int q = 0; q < 4; q++) {
    float p = 0.f;
    #pragma unroll
    for (int kf = 0; kf < 4; kf++) p += fgelu(acc[q][kf]) * wo[kf];
    red[fy][4 * ny + q] = p;
  }
  __syncthreads();
  if (threadIdx.x < 64) {
    int n = nb + threadIdx.x;
    if (n < NN) {
      float e = 0.f;
      #pragma unroll
      for (int fy2 = 0; fy2 < 16; fy2++) e += red[fy2][threadIdx.x];
      if (fb == 0) e += b_out1[0];
      atomicAdd(&gacc[batch[n]], e);
    }
  }
  __syncthreads();
  if (threadIdx.x < GG && gacc[threadIdx.x] != 0.f)
    atomicAdd(&graph[threadIdx.x], gacc[threadIdx.x]);
}

__global__ void k_finalize(const float* __restrict__ graph, const float* __restrict__ W_read,
                           const float* __restrict__ b_read, float* __restrict__ out) {
  int g = threadIdx.x;
  if (g < GG) out[g] = graph[g] * W_read[0] + b_read[0];
}

// ---------------- host ----------------
extern "C" void kernel_launch(void* const* d_in, const int* in_sizes, int n_in,
                              void* d_out, int out_size, void* d_ws, size_t ws_size,
                              hipStream_t stream) {
  const float* pos = (const float*)d_in[0];
  const int* node_atom = (const int*)d_in[1];
  const int* batch = (const int*)d_in[2];
  const int* esrc = (const int*)d_in[3];
  const int* edst = (const int*)d_in[4];
  const float* atom_emb = (const float*)d_in[5];
  const float* Wrad1 = (const float*)d_in[6];
  const float* brad1 = (const float*)d_in[7];
  const float* Wrad2 = (const float*)d_in[8];
  const float* brad2 = (const float*)d_in[9];
  const float* Ws_src = (const float*)d_in[10];
  const float* Ww_s = (const float*)d_in[11];
  const float* Ws_v = (const float*)d_in[12];
  const float* Ww_v = (const float*)d_in[13];
  const float* Wv_v = (const float*)d_in[14];
  const float* Ww_vv = (const float*)d_in[15];
  const float* Ws_t = (const float*)d_in[16];
  const float* Ww_t = (const float*)d_in[17];
  const float* Wt_t = (const float*)d_in[18];
  const float* Ww_tt = (const float*)d_in[19];
  const float* attn_a = (const float*)d_in[20];
  const float* Wo_s = (const float*)d_in[21];
  const float* Wo_v = (const float*)d_in[22];
  const float* Wo_t = (const float*)d_in[23];
  const float* g_s = (const float*)d_in[24];
  const float* b_s = (const float*)d_in[25];
  const float* g_v = (const float*)d_in[26];
  const float* g_t = (const float*)d_in[27];
  const float* W_feat = (const float*)d_in[28];
  const float* b_feat = (const float*)d_in[29];
  const float* W_out1 = (const float*)d_in[30];
  const float* b_out1 = (const float*)d_in[31];
  const float* W_read = (const float*)d_in[32];
  const float* b_read = (const float*)d_in[33];
  float* out = (float*)d_out;

  char* base = (char*)d_ws;
  size_t off = 0;
  auto alloc = [&](size_t bytes) -> char* {
    off = (off + 255) & ~(size_t)255;
    char* p = base + off;
    off += bytes;
    return p;
  };
  int* deg = (int*)alloc(NN * 4);
  int* row_off = (int*)alloc((NN + 1) * 4);
  int* cursor = (int*)alloc(NN * 4);
  int* perm = (int*)alloc((size_t)EE * 4);
  float* d_csr = (float*)alloc((size_t)EE * 4);
  int* acnt = (int*)alloc(NN * 4);
  int* act_off = (int*)alloc((NN + 1) * 4);
  int* act_idx = (int*)alloc((size_t)EE * 4);
  float* d_a = (float*)alloc((size_t)EE * 4);
  int* src_a = (int*)alloc((size_t)EE * 4);
  float* sh_a = (float*)alloc((size_t)EE * 8 * 4);
  float* wtab = (float*)alloc((size_t)LL * TABN * 64 * 4);
  float* logitb = (float*)alloc((size_t)EE * 4 * 4);
  float* qv = (float*)alloc((size_t)NN * 256 * 4);
  float* s = (float*)alloc((size_t)NN * 128 * 4);
  float* v = (float*)alloc((size_t)NN * 192 * 4);
  float* t = (float*)alloc((size_t)NN * 160 * 4);
  float* sWsrc = (float*)alloc((size_t)NN * 128 * 4);
  float* sWv = (float*)alloc((size_t)NN * 64 * 4);
  float* sWt = (float*)alloc((size_t)NN * 32 * 4);
  float* vW = (float*)alloc((size_t)NN * 192 * 4);
  float* tW = (float*)alloc((size_t)NN * 160 * 4);
  float* agg_s = (float*)alloc((size_t)NN * 128 * 4);
  float* agg_v = (float*)alloc((size_t)NN * 192 * 4);
  float* agg_t = (float*)alloc((size_t)NN * 160 * 4);
  float* graph = (float*)alloc(GG * 4);

  hipMemsetAsync(deg, 0, NN * 4, stream);
  hipMemsetAsync(cursor, 0, NN * 4, stream);
  hipMemsetAsync(graph, 0, GG * 4, stream);
  hipMemsetAsync(v, 0, (size_t)NN * 192 * 4, stream);
  hipMemsetAsync(t, 0, (size_t)NN * 160 * 4, stream);

  k_hist<<<(EE + 255) / 256, 256, 0, stream>>>(edst, deg);
  k_scan<<<1, 1024, 0, stream>>>(deg, row_off, NN);
  k_scatter<<<(EE + 255) / 256, 256, 0, stream>>>(edst, row_off, cursor, perm);
  k_geom_d<<<(EE + 255) / 256, 256, 0, stream>>>(pos, esrc, edst, perm, d_csr);
  k_act_cnt<<<(NN + 255) / 256, 256, 0, stream>>>(row_off, d_csr, acnt);
  k_scan<<<1, 1024, 0, stream>>>(acnt, act_off, NN);
  k_act_fill<<<(NN + 255) / 256, 256, 0, stream>>>(row_off, d_csr, act_off, act_idx);
  k_geom_act<<<(EE + 255) / 256, 256, 0, stream>>>(act_idx, perm, esrc, edst, pos, act_off,
                                                   d_a, src_a, sh_a);
  k_build_wtab<<<LL * 64, 256, 0, stream>>>(Wrad1, brad1, Wrad2, brad2, wtab);
  k_init_s<<<(NN * 128 + 255) / 256, 256, 0, stream>>>(node_atom, atom_emb, s);

  for (int l = 0; l < LL; l++) {
    const float* wtabL = wtab + (size_t)l * TABN * 64;
    k_node_tf<<<NN / 16, 256, 0, stream>>>(
        s, v, t, Ws_src + (size_t)l * 128 * 128, Ws_v + (size_t)l * 128 * 64,
        Ws_t + (size_t)l * 128 * 32, Wv_v + (size_t)l * 64 * 64, Wt_t + (size_t)l * 32 * 32,
        sWsrc, sWv, sWt, vW, tW);
    k_qvec<<<NN / 16, 256, 0, stream>>>(sWsrc, Ww_s + (size_t)l * 64 * 128,
                                        attn_a + (size_t)l * 128, qv);
    k_logit<<<512, 256, 0, stream>>>(d_a, src_a, act_off, wtabL, qv, logitb);
    k_fused_s<<<NN / 8, 512, 0, stream>>>(row_off, act_off, src_a, d_a, logitb, wtabL,
                                          sWsrc, Ww_s + (size_t)l * 64 * 128, agg_s);
    k_fused_vt<<<NN / 8, 512, 0, stream>>>(row_off, act_off, src_a, d_a, logitb, wtabL,
                                           sWv, sWt, vW, tW, sh_a,
                                           Ww_v + (size_t)l * 64 * 64, Ww_vv + (size_t)l * 64 * 64,
                                           Ww_t + (size_t)l * 64 * 32, Ww_tt + (size_t)l * 64 * 32,
                                           agg_v, agg_t);
    k_node_up<<<NN / 16, 256, 0, stream>>>(s, v, t, agg_s, agg_v, agg_t,
                                           Wo_s + (size_t)l * 128 * 128,
                                           Wo_v + (size_t)l * 64 * 64, Wo_t + (size_t)l * 32 * 32,
                                           g_s + (size_t)l * 128, b_s + (size_t)l * 128,
                                           g_v + (size_t)l * 64, g_t + (size_t)l * 32);
  }
  dim3 rg((NN + 63) / 64, 8);
  k_readout<<<rg, 256, 0, stream>>>(s, batch, W_feat, b_feat, W_out1, b_out1, graph);
  k_finalize<<<1, 64, 0, stream>>>(graph, W_read, b_read, out);
}